// Round 1
// baseline (1019.670 us; speedup 1.0000x reference)
//
#include <hip/hip_runtime.h>
#include <cstdint>
#include <cstddef>

// Problem constants (fixed by the reference)
#define B_  2
#define T_  1024
#define C_  2048
#define H_  32
#define BT_ (B_*T_)
static constexpr float EPS_GN = 1e-5f * 64.0f;

using short8 = __attribute__((ext_vector_type(8))) short;
using f32x4  = __attribute__((ext_vector_type(4))) float;
typedef unsigned short bfu16;

__device__ __forceinline__ bfu16 f2b(float f) {
  uint32_t x = __float_as_uint(f);
  uint32_t r = (x + 0x7FFFu + ((x >> 16) & 1u)) >> 16;
  return (bfu16)r;
}
__device__ __forceinline__ float b2f(bfu16 h) {
  return __uint_as_float(((uint32_t)h) << 16);
}

__device__ __forceinline__ void gload16(const bfu16* g, bfu16* l) {
  __builtin_amdgcn_global_load_lds((__attribute__((address_space(1))) void*)g,
                                   (__attribute__((address_space(3))) void*)l,
                                   16, 0, 0);
}

// ---------------------------------------------------------------------------
// Generic bf16 MFMA GEMM: C[M,N] = A[M,K] @ B[K,N], B supplied pre-transposed
// as Bt[N,K] (row-major, bf16). Tile 128x128, BK=64, 4 waves of 2x2x(4x4 frags).
// EPI: 0 = f32 out, 1 = tanh->scatter to mtan[5][BT][64], 2 = token-mix bf16,
//      3 = tanh->bf16 [BT][64], 4 = +time_decay f32.
// ---------------------------------------------------------------------------
struct EpiArgs {
  float* of;
  bfu16* ob;
  const float* x;
  const float* xx;
  const float* vec;
  int nout;
  int ldo;
};

template<int EPI>
__global__ __launch_bounds__(256)
void gemm_bt(const bfu16* __restrict__ A, const bfu16* __restrict__ Bt,
             int M, int K, EpiArgs e)
{
  __shared__ alignas(16) bfu16 As[128*64];
  __shared__ alignas(16) bfu16 Bs[128*64];
  const int tid  = threadIdx.x;
  const int m0   = blockIdx.y * 128, n0 = blockIdx.x * 128;
  const int lane = tid & 63;
  const int wv   = tid >> 6;
  const int wr   = (wv >> 1) * 64, wc = (wv & 1) * 64;

  f32x4 acc[4][4];
  const f32x4 zero = {0.f, 0.f, 0.f, 0.f};
#pragma unroll
  for (int i = 0; i < 4; ++i)
#pragma unroll
    for (int j = 0; j < 4; ++j) acc[i][j] = zero;

  const int srow = tid >> 3;        // 0..31
  const int scol = (tid & 7) * 8;   // 0..56

  for (int k0 = 0; k0 < K; k0 += 64) {
    const bfu16* ga = A  + (size_t)m0 * K + k0;
    const bfu16* gb = Bt + (size_t)n0 * K + k0;
#pragma unroll
    for (int it = 0; it < 4; ++it) {
      int r = it * 32 + srow;
      gload16(ga + (size_t)r * K + scol, As + r * 64 + scol);
      gload16(gb + (size_t)r * K + scol, Bs + r * 64 + scol);
    }
    __syncthreads();
#pragma unroll
    for (int kk = 0; kk < 2; ++kk) {
      const int ko = kk * 32 + (lane >> 4) * 8;
      short8 a[4], b[4];
#pragma unroll
      for (int i = 0; i < 4; ++i)
        a[i] = *(const short8*)(As + (wr + i * 16 + (lane & 15)) * 64 + ko);
#pragma unroll
      for (int j = 0; j < 4; ++j)
        b[j] = *(const short8*)(Bs + (wc + j * 16 + (lane & 15)) * 64 + ko);
#pragma unroll
      for (int i = 0; i < 4; ++i)
#pragma unroll
        for (int j = 0; j < 4; ++j)
          acc[i][j] = __builtin_amdgcn_mfma_f32_16x16x32_bf16(a[i], b[j], acc[i][j], 0, 0, 0);
    }
    __syncthreads();
  }

  const int cb = n0 + wc + (lane & 15);
  const int rb = m0 + wr + ((lane >> 4) << 2);
#pragma unroll
  for (int i = 0; i < 4; ++i) {
#pragma unroll
    for (int j = 0; j < 4; ++j) {
      int col = cb + j * 16;
#pragma unroll
      for (int q = 0; q < 4; ++q) {
        int row = rb + i * 16 + q;
        float v = acc[i][j][q];
        if constexpr (EPI == 0) {
          e.of[(size_t)row * e.ldo + col] = v;
        } else if constexpr (EPI == 1) {          // tanh -> mtan[f][row][d]
          if (col < e.nout) {
            int f = col >> 5, d = col & 31;
            e.ob[((size_t)f * BT_ + row) * 64 + d] = f2b(tanhf(v));
          }
        } else if constexpr (EPI == 2) {          // x + xx*(maa + m)
          size_t idx = (size_t)row * C_ + col;
          e.ob[idx] = f2b(e.x[idx] + e.xx[idx] * (e.vec[col] + v));
        } else if constexpr (EPI == 3) {          // tanh -> wtan[row][col]
          if (col < e.nout) e.ob[(size_t)row * 64 + col] = f2b(tanhf(v));
        } else {                                   // time_decay + acc
          e.of[(size_t)row * C_ + col] = e.vec[col] + v;
        }
      }
    }
  }
}

// ---------------------------------------------------------------------------
// f32 [R][Cc] -> bf16 dst[c*ldd + r]  (transpose + downconvert); pad rows of
// dst beyond Cc / cols beyond R are handled by memset outside.
// ---------------------------------------------------------------------------
__global__ __launch_bounds__(256)
void transpose_f2b(const float* __restrict__ src, bfu16* __restrict__ dst,
                   int R, int Cc, int ldd)
{
  __shared__ float tile[32][33];
  const int tx = threadIdx.x & 31, ty = threadIdx.x >> 5;
  const int r0 = blockIdx.y * 32, c0 = blockIdx.x * 32;
#pragma unroll
  for (int i = 0; i < 4; ++i) {
    int r = r0 + ty + i * 8, c = c0 + tx;
    tile[ty + i * 8][tx] = (r < R && c < Cc) ? src[(size_t)r * Cc + c] : 0.f;
  }
  __syncthreads();
#pragma unroll
  for (int i = 0; i < 4; ++i) {
    int c = c0 + ty + i * 8, r = r0 + tx;
    if (c < Cc && r < R) dst[(size_t)c * ldd + r] = f2b(tile[tx][ty + i * 8]);
  }
}

// ---------------------------------------------------------------------------
// xx = shift(x) - x ; xxx = bf16(x + xx*maa_x)
// ---------------------------------------------------------------------------
__global__ __launch_bounds__(256)
void prep_xx(const float* __restrict__ x, const float* __restrict__ maa_x,
             float* __restrict__ xx, bfu16* __restrict__ xxx)
{
  size_t i = ((size_t)blockIdx.x * 256 + threadIdx.x) * 4;
  int c  = (int)(i & (C_ - 1));
  int bt = (int)(i >> 11);
  int t  = bt & (T_ - 1);
  float4 xv = *(const float4*)(x + i);
  float4 xp = {0.f, 0.f, 0.f, 0.f};
  if (t > 0) xp = *(const float4*)(x + i - C_);
  float4 mx = *(const float4*)(maa_x + c);
  float4 d;
  d.x = xp.x - xv.x; d.y = xp.y - xv.y; d.z = xp.z - xv.z; d.w = xp.w - xv.w;
  *(float4*)(xx + i) = d;
  xxx[i + 0] = f2b(xv.x + d.x * mx.x);
  xxx[i + 1] = f2b(xv.y + d.y * mx.y);
  xxx[i + 2] = f2b(xv.z + d.z * mx.z);
  xxx[i + 3] = f2b(xv.w + d.w * mx.w);
}

// ---------------------------------------------------------------------------
// WKV6 recurrence. 64 blocks (b,h), 256 threads: i = tid&63 (value column),
// jg = tid>>6 (key-row group of 16). S[j][i] lives in regs (16 per thread).
// Register prefetch of t+1 inputs hides HBM latency under the step.
// ---------------------------------------------------------------------------
__global__ __launch_bounds__(256)
void wkv_kernel(const float* __restrict__ r, const float* __restrict__ k,
                const float* __restrict__ v, const float* __restrict__ w,
                const float* __restrict__ u, float* __restrict__ y)
{
  const int blk = blockIdx.x;
  const int b = blk >> 5, h = blk & 31;
  const int tid = threadIdx.x;
  const int i  = tid & 63;
  const int jg = tid >> 6;
  __shared__ float r_s[64], k_s[64], d_s[64], v_s[64];
  __shared__ float red[4][64][2];
  float S[16];
  float ur[16];
#pragma unroll
  for (int jj = 0; jj < 16; ++jj) S[jj] = 0.f;
#pragma unroll
  for (int jj = 0; jj < 16; ++jj) ur[jj] = u[h * 64 + jg * 16 + jj];

  const float* src = (jg == 0) ? r : (jg == 1) ? k : (jg == 2) ? w : v;
  const size_t base0 = ((size_t)b * T_) * C_ + h * 64 + i;
  float held = src[base0];

  for (int t = 0; t < T_; ++t) {
    if      (jg == 0) r_s[i] = held;
    else if (jg == 1) k_s[i] = held;
    else if (jg == 2) d_s[i] = __expf(-__expf(held));
    else              v_s[i] = held;
    if (t + 1 < T_) held = src[base0 + (size_t)(t + 1) * C_];
    __syncthreads();
    float vi = v_s[i];
    float py = 0.f, pu = 0.f;
#pragma unroll
    for (int jj = 0; jj < 16; ++jj) {
      int j = jg * 16 + jj;
      float rj = r_s[j], kj = k_s[j], dj = d_s[j];
      py += rj * S[jj];
      pu += rj * ur[jj] * kj;
      S[jj] = dj * S[jj] + kj * vi;
    }
    red[jg][i][0] = py;
    red[jg][i][1] = pu;
    __syncthreads();
    if (jg == 0) {
      float ys = red[0][i][0] + red[1][i][0] + red[2][i][0] + red[3][i][0];
      float us = red[0][i][1] + red[1][i][1] + red[2][i][1] + red[3][i][1];
      y[((size_t)(b * T_ + t)) * C_ + h * 64 + i] = ys + us * vi;
    }
  }
}

// ---------------------------------------------------------------------------
// GroupNorm(32 groups of 64) * silu(gpre) -> bf16
// ---------------------------------------------------------------------------
__global__ __launch_bounds__(256)
void gnorm_kernel(const float* __restrict__ y, const float* __restrict__ gpre,
                  const float* __restrict__ lng, const float* __restrict__ lnb,
                  bfu16* __restrict__ yg)
{
  const int bt = blockIdx.x;
  const int wv = threadIdx.x >> 6, lane = threadIdx.x & 63;
#pragma unroll
  for (int it = 0; it < 8; ++it) {
    int hh = it * 4 + wv;
    int c = hh * 64 + lane;
    size_t idx = (size_t)bt * C_ + c;
    float yv = y[idx];
    float s = yv, sq = yv * yv;
#pragma unroll
    for (int m = 1; m < 64; m <<= 1) {
      s  += __shfl_xor(s, m, 64);
      sq += __shfl_xor(sq, m, 64);
    }
    float mu  = s * (1.f / 64.f);
    float var = sq * (1.f / 64.f) - mu * mu;
    float yn  = (yv - mu) * rsqrtf(var + EPS_GN);
    yn = yn * lng[c] + lnb[c];
    float gp = gpre[idx];
    float gs = gp / (1.f + __expf(-gp));
    yg[idx] = f2b(yn * gs);
  }
}

// ---------------------------------------------------------------------------
extern "C" void kernel_launch(void* const* d_in, const int* in_sizes, int n_in,
                              void* d_out, int out_size, void* d_ws, size_t ws_size,
                              hipStream_t stream)
{
  const float* x      = (const float*)d_in[0];
  const float* maa_x  = (const float*)d_in[1];
  const float* maa_w  = (const float*)d_in[2];
  const float* maa_k  = (const float*)d_in[3];
  const float* maa_v  = (const float*)d_in[4];
  const float* maa_r  = (const float*)d_in[5];
  const float* maa_g  = (const float*)d_in[6];
  const float* tdec   = (const float*)d_in[7];
  const float* u      = (const float*)d_in[8];
  const float* maa_w1 = (const float*)d_in[9];
  const float* maa_w2 = (const float*)d_in[10];
  const float* td_w1  = (const float*)d_in[11];
  const float* td_w2  = (const float*)d_in[12];
  const float* Wmats[5] = { (const float*)d_in[13], (const float*)d_in[14],
                            (const float*)d_in[15], (const float*)d_in[16],
                            (const float*)d_in[17] };
  const float* lng = (const float*)d_in[18];
  const float* lnb = (const float*)d_in[19];
  float* out = (float*)d_out;

  char* wsp = (char*)d_ws;
  auto alloc = [&](size_t bytes) -> char* {
    char* p = wsp;
    wsp += (bytes + 255) & ~(size_t)255;
    return p;
  };

  bfu16* WT[5];
  for (int i = 0; i < 5; ++i) WT[i] = (bfu16*)alloc((size_t)2048 * 2048 * 2);
  bfu16* w1T  = (bfu16*)alloc((size_t)256 * 2048 * 2);   // maa_w1^T padded 160->256 rows
  bfu16* tw1T = (bfu16*)alloc((size_t)128 * 2048 * 2);   // td_w1^T padded 64->128 rows
  bfu16* tw2T = (bfu16*)alloc((size_t)2048 * 64 * 2);    // td_w2^T
  bfu16* w2T  = (bfu16*)alloc((size_t)5 * 2048 * 64 * 2);// maa_w2^T per f, K-pad 32->64
  float* xxb  = (float*)alloc((size_t)BT_ * C_ * 4);
  bfu16* xxx  = (bfu16*)alloc((size_t)BT_ * C_ * 2);
  bfu16* mtan = (bfu16*)alloc((size_t)5 * BT_ * 64 * 2); // tanh(xxx@maa_w1), K-pad
  bfu16* xmix[5];
  for (int f = 0; f < 5; ++f) xmix[f] = (bfu16*)alloc((size_t)BT_ * C_ * 2);
  float* rbuf = (float*)alloc((size_t)BT_ * C_ * 4);
  float* kbuf = (float*)alloc((size_t)BT_ * C_ * 4);
  float* vbuf = (float*)alloc((size_t)BT_ * C_ * 4);
  float* gbuf = (float*)alloc((size_t)BT_ * C_ * 4);
  float* wbuf = (float*)alloc((size_t)BT_ * C_ * 4);
  bfu16* wtan = (bfu16*)alloc((size_t)BT_ * 64 * 2);
  // y aliases xx (dead by then); yg aliases xxx (dead by then)
  float* ybuf = (float*)xxb;
  bfu16* ygb  = xxx;

  // Zero the K/N pad regions (deterministic every call)
  hipMemsetAsync(w1T,  0, (size_t)256 * 2048 * 2, stream);
  hipMemsetAsync(tw1T, 0, (size_t)128 * 2048 * 2, stream);
  hipMemsetAsync(w2T,  0, (size_t)5 * 2048 * 64 * 2, stream);
  hipMemsetAsync(mtan, 0, (size_t)5 * BT_ * 64 * 2, stream);

  dim3 tb(256);
  auto tr = [&](const float* s, bfu16* dptr, int R, int Cc, int ldd) {
    dim3 g((Cc + 31) / 32, (R + 31) / 32);
    transpose_f2b<<<g, tb, 0, stream>>>(s, dptr, R, Cc, ldd);
  };
  for (int i = 0; i < 5; ++i) tr(Wmats[i], WT[i], 2048, 2048, 2048);
  tr(maa_w1, w1T, 2048, 160, 2048);
  tr(td_w1, tw1T, 2048, 64, 2048);
  tr(td_w2, tw2T, 64, 2048, 64);
  for (int f = 0; f < 5; ++f)
    tr(maa_w2 + (size_t)f * 32 * 2048, w2T + (size_t)f * 2048 * 64, 32, 2048, 64);

  // token shift + xxx
  prep_xx<<<dim3((BT_ * C_ / 4) / 256), tb, 0, stream>>>(x, maa_x, xxb, xxx);

  // m = tanh(xxx @ maa_w1)  -> mtan[5][BT][64] scatter
  {
    EpiArgs e{}; e.ob = mtan; e.nout = 160;
    gemm_bt<1><<<dim3(2, 16), tb, 0, stream>>>(xxx, w1T, BT_, 2048, e);
  }

  // einsum + token-mix epilogue: xmix[f] = bf16(x + xx*(maa_f + m_f))
  const float* maas[5] = { maa_w, maa_k, maa_v, maa_r, maa_g };
  for (int f = 0; f < 5; ++f) {
    EpiArgs e{}; e.ob = xmix[f]; e.x = x; e.xx = xxb; e.vec = maas[f]; e.nout = 2048;
    gemm_bt<2><<<dim3(16, 16), tb, 0, stream>>>(mtan + (size_t)f * BT_ * 64,
                                                w2T + (size_t)f * 2048 * 64, BT_, 64, e);
  }

  // r,k,v,gpre big GEMMs (xr=f3, xk=f1, xv=f2, xg=f4)
  {
    EpiArgs e{}; e.ldo = 2048;
    e.of = rbuf; gemm_bt<0><<<dim3(16, 16), tb, 0, stream>>>(xmix[3], WT[0], BT_, 2048, e);
    e.of = kbuf; gemm_bt<0><<<dim3(16, 16), tb, 0, stream>>>(xmix[1], WT[1], BT_, 2048, e);
    e.of = vbuf; gemm_bt<0><<<dim3(16, 16), tb, 0, stream>>>(xmix[2], WT[2], BT_, 2048, e);
    e.of = gbuf; gemm_bt<0><<<dim3(16, 16), tb, 0, stream>>>(xmix[4], WT[3], BT_, 2048, e);
  }

  // w path: wtan = tanh(xw @ td_w1) ; w = time_decay + wtan @ td_w2
  {
    EpiArgs e{}; e.ob = wtan; e.nout = 64;
    gemm_bt<3><<<dim3(1, 16), tb, 0, stream>>>(xmix[0], tw1T, BT_, 2048, e);
  }
  {
    EpiArgs e{}; e.of = wbuf; e.vec = tdec;
    gemm_bt<4><<<dim3(16, 16), tb, 0, stream>>>(wtan, tw2T, BT_, 64, e);
  }

  // recurrence
  wkv_kernel<<<dim3(64), tb, 0, stream>>>(rbuf, kbuf, vbuf, wbuf, u, ybuf);

  // GroupNorm * silu(g)
  gnorm_kernel<<<dim3(BT_), tb, 0, stream>>>(ybuf, gbuf, lng, lnb, ygb);

  // out = yg @ Wo
  {
    EpiArgs e{}; e.of = out; e.ldo = 2048;
    gemm_bt<0><<<dim3(16, 16), tb, 0, stream>>>(ygb, WT[4], BT_, 2048, e);
  }
}

// Round 2
// 552.331 us; speedup vs baseline: 1.8461x; 1.8461x over previous
//
#include <hip/hip_runtime.h>
#include <cstdint>
#include <cstddef>

// Problem constants (fixed by the reference)
#define B_  2
#define T_  1024
#define C_  2048
#define H_  32
#define BT_ (B_*T_)
static constexpr float EPS_GN = 1e-5f * 64.0f;

using short8 = __attribute__((ext_vector_type(8))) short;
using f32x4  = __attribute__((ext_vector_type(4))) float;
typedef unsigned short bfu16;

__device__ __forceinline__ bfu16 f2b(float f) {
  uint32_t x = __float_as_uint(f);
  uint32_t r = (x + 0x7FFFu + ((x >> 16) & 1u)) >> 16;
  return (bfu16)r;
}
__device__ __forceinline__ float b2f(bfu16 h) {
  return __uint_as_float(((uint32_t)h) << 16);
}

__device__ __forceinline__ void gload16(const bfu16* g, bfu16* l) {
  __builtin_amdgcn_global_load_lds((__attribute__((address_space(1))) void*)g,
                                   (__attribute__((address_space(3))) void*)l,
                                   16, 0, 0);
}

// ---------------------------------------------------------------------------
// Generic bf16 MFMA GEMM: C[M,N] = A[M,K] @ B[K,N], B supplied pre-transposed
// as Bt[N,K] (row-major, bf16). Tile 128x128, BK=64, 4 waves of 2x2x(4x4 frags).
// ---------------------------------------------------------------------------
struct EpiArgs {
  float* of;
  bfu16* ob;
  const float* x;
  const float* xx;
  const float* vec;
  int nout;
  int ldo;
};

template<int EPI>
__global__ __launch_bounds__(256)
void gemm_bt(const bfu16* __restrict__ A, const bfu16* __restrict__ Bt,
             int M, int K, EpiArgs e)
{
  __shared__ alignas(16) bfu16 As[128*64];
  __shared__ alignas(16) bfu16 Bs[128*64];
  const int tid  = threadIdx.x;
  const int m0   = blockIdx.y * 128, n0 = blockIdx.x * 128;
  const int lane = tid & 63;
  const int wv   = tid >> 6;
  const int wr   = (wv >> 1) * 64, wc = (wv & 1) * 64;

  f32x4 acc[4][4];
  const f32x4 zero = {0.f, 0.f, 0.f, 0.f};
#pragma unroll
  for (int i = 0; i < 4; ++i)
#pragma unroll
    for (int j = 0; j < 4; ++j) acc[i][j] = zero;

  const int srow = tid >> 3;        // 0..31
  const int scol = (tid & 7) * 8;   // 0..56

  for (int k0 = 0; k0 < K; k0 += 64) {
    const bfu16* ga = A  + (size_t)m0 * K + k0;
    const bfu16* gb = Bt + (size_t)n0 * K + k0;
#pragma unroll
    for (int it = 0; it < 4; ++it) {
      int r = it * 32 + srow;
      gload16(ga + (size_t)r * K + scol, As + r * 64 + scol);
      gload16(gb + (size_t)r * K + scol, Bs + r * 64 + scol);
    }
    __syncthreads();
#pragma unroll
    for (int kk = 0; kk < 2; ++kk) {
      const int ko = kk * 32 + (lane >> 4) * 8;
      short8 a[4], b[4];
#pragma unroll
      for (int i = 0; i < 4; ++i)
        a[i] = *(const short8*)(As + (wr + i * 16 + (lane & 15)) * 64 + ko);
#pragma unroll
      for (int j = 0; j < 4; ++j)
        b[j] = *(const short8*)(Bs + (wc + j * 16 + (lane & 15)) * 64 + ko);
#pragma unroll
      for (int i = 0; i < 4; ++i)
#pragma unroll
        for (int j = 0; j < 4; ++j)
          acc[i][j] = __builtin_amdgcn_mfma_f32_16x16x32_bf16(a[i], b[j], acc[i][j], 0, 0, 0);
    }
    __syncthreads();
  }

  const int cb = n0 + wc + (lane & 15);
  const int rb = m0 + wr + ((lane >> 4) << 2);
#pragma unroll
  for (int i = 0; i < 4; ++i) {
#pragma unroll
    for (int j = 0; j < 4; ++j) {
      int col = cb + j * 16;
#pragma unroll
      for (int q = 0; q < 4; ++q) {
        int row = rb + i * 16 + q;
        float v = acc[i][j][q];
        if constexpr (EPI == 0) {
          e.of[(size_t)row * e.ldo + col] = v;
        } else if constexpr (EPI == 1) {          // tanh -> mtan[f][row][d]
          if (col < e.nout) {
            int f = col >> 5, d = col & 31;
            e.ob[((size_t)f * BT_ + row) * 64 + d] = f2b(tanhf(v));
          }
        } else if constexpr (EPI == 2) {          // x + xx*(maa + m)
          size_t idx = (size_t)row * C_ + col;
          e.ob[idx] = f2b(e.x[idx] + e.xx[idx] * (e.vec[col] + v));
        } else if constexpr (EPI == 3) {          // tanh -> wtan[row][col]
          if (col < e.nout) e.ob[(size_t)row * 64 + col] = f2b(tanhf(v));
        } else {                                   // time_decay + acc
          e.of[(size_t)row * C_ + col] = e.vec[col] + v;
        }
      }
    }
  }
}

// ---------------------------------------------------------------------------
// f32 [R][Cc] -> bf16 dst[c*ldd + r]  (transpose + downconvert)
// ---------------------------------------------------------------------------
__global__ __launch_bounds__(256)
void transpose_f2b(const float* __restrict__ src, bfu16* __restrict__ dst,
                   int R, int Cc, int ldd)
{
  __shared__ float tile[32][33];
  const int tx = threadIdx.x & 31, ty = threadIdx.x >> 5;
  const int r0 = blockIdx.y * 32, c0 = blockIdx.x * 32;
#pragma unroll
  for (int i = 0; i < 4; ++i) {
    int r = r0 + ty + i * 8, c = c0 + tx;
    tile[ty + i * 8][tx] = (r < R && c < Cc) ? src[(size_t)r * Cc + c] : 0.f;
  }
  __syncthreads();
#pragma unroll
  for (int i = 0; i < 4; ++i) {
    int c = c0 + ty + i * 8, r = r0 + tx;
    if (c < Cc && r < R) dst[(size_t)c * ldd + r] = f2b(tile[tx][ty + i * 8]);
  }
}

// ---------------------------------------------------------------------------
// xx = shift(x) - x ; xxx = bf16(x + xx*maa_x)
// ---------------------------------------------------------------------------
__global__ __launch_bounds__(256)
void prep_xx(const float* __restrict__ x, const float* __restrict__ maa_x,
             float* __restrict__ xx, bfu16* __restrict__ xxx)
{
  size_t i = ((size_t)blockIdx.x * 256 + threadIdx.x) * 4;
  int c  = (int)(i & (C_ - 1));
  int bt = (int)(i >> 11);
  int t  = bt & (T_ - 1);
  float4 xv = *(const float4*)(x + i);
  float4 xp = {0.f, 0.f, 0.f, 0.f};
  if (t > 0) xp = *(const float4*)(x + i - C_);
  float4 mx = *(const float4*)(maa_x + c);
  float4 d;
  d.x = xp.x - xv.x; d.y = xp.y - xv.y; d.z = xp.z - xv.z; d.w = xp.w - xv.w;
  *(float4*)(xx + i) = d;
  xxx[i + 0] = f2b(xv.x + d.x * mx.x);
  xxx[i + 1] = f2b(xv.y + d.y * mx.y);
  xxx[i + 2] = f2b(xv.z + d.z * mx.z);
  xxx[i + 3] = f2b(xv.w + d.w * mx.w);
}

// ---------------------------------------------------------------------------
// WKV6 chunked scan. Chunk L=64. Phase A (1024 blocks = B*H*16 chunks):
// log-space cumulative decay, intra-chunk causal attention (f32 VALU),
// chunk summaries G (decay) and U (k''^T V). Writes r' in-place over r.
// Phase B (64 blocks): 16-step state scan S_{c+1} = G_c*S_c + U_c.
// Phase C (1024 blocks): y += r' @ S_chunkstart.
// ---------------------------------------------------------------------------
#define STR 76   // LDS row stride (floats): 16B-aligned, bank-friendly

__global__ __launch_bounds__(256)
void wkv_a(const float* __restrict__ r, const float* __restrict__ k,
           const float* __restrict__ v, const float* __restrict__ w,
           const float* __restrict__ u, float* __restrict__ rp,
           float* __restrict__ y, float* __restrict__ U, float* __restrict__ G)
{
  __shared__ float rw[64 * STR];   // r, then r' = r*exp(cs_t)
  __shared__ float kk[64 * STR];   // k, then k~ = k*exp(-cs_{t+1})
  __shared__ float vv[64 * STR];   // v
  __shared__ float Ps[64 * STR];   // lw, then D (diag products), then scores
  __shared__ float red[4][64];
  __shared__ float diag[64];
  __shared__ float Gl[64];

  const int blk = blockIdx.x;
  const int bh = blk >> 4, c = blk & 15;
  const int b = bh >> 5, h = bh & 31;
  const int tid = threadIdx.x;
  const size_t gbase = ((size_t)(b * T_ + c * 64)) * C_ + h * 64;

  // ---- load r,k,v and lw = -exp(w)
  {
    const int t = tid >> 2, q = tid & 3;
    const size_t g = gbase + (size_t)t * C_ + q * 16;
    const int l = t * STR + q * 16;
#pragma unroll
    for (int p = 0; p < 4; ++p) {
      *(float4*)(rw + l + p * 4) = *(const float4*)(r + g + p * 4);
      *(float4*)(kk + l + p * 4) = *(const float4*)(k + g + p * 4);
      *(float4*)(vv + l + p * 4) = *(const float4*)(v + g + p * 4);
      float4 wv = *(const float4*)(w + g + p * 4);
      float4 lw;
      lw.x = -__expf(wv.x); lw.y = -__expf(wv.y);
      lw.z = -__expf(wv.z); lw.w = -__expf(wv.w);
      *(float4*)(Ps + l + p * 4) = lw;
    }
  }
  __syncthreads();

  // ---- per-j serial prefix over t: scale r,k in place; D into Ps; G out
  if (tid < 64) {
    const int j = tid;
    const float uj = u[h * 64 + j];
    float cs = 0.f;
    for (int t = 0; t < 64; ++t) {
      const int a = t * STR + j;
      float lw = Ps[a];
      float rv = rw[a] * __expf(cs);
      rw[a] = rv;
      cs += lw;
      float kv = kk[a] * __expf(-cs);
      kk[a] = kv;
      Ps[a] = rv * kv * uj * __expf(lw);   // = r*k*u (exact)
    }
    float Gj = __expf(cs);
    Gl[j] = Gj;
    G[((size_t)bh * 16 + c) * 64 + j] = Gj;
  }
  __syncthreads();

  // ---- diag[t] = sum_j D[t][j]
  {
    const int t = tid & 63, q = tid >> 6;
    float s = 0.f;
#pragma unroll
    for (int jj = 0; jj < 16; ++jj) s += Ps[t * STR + q * 16 + jj];
    red[q][t] = s;
  }
  __syncthreads();
  if (tid < 64) diag[tid] = red[0][tid] + red[1][tid] + red[2][tid] + red[3][tid];
  __syncthreads();

  // ---- scores P[t][s] = r'_t . k~_s  (s<t), diag on s==t, 0 above
  {
    const int tq = tid >> 4, sq = tid & 15;
    float acc[4][4] = {{0.f}};
    if (sq <= tq) {
      for (int j = 0; j < 64; j += 4) {
        float4 a0 = *(const float4*)(rw + (tq * 4 + 0) * STR + j);
        float4 a1 = *(const float4*)(rw + (tq * 4 + 1) * STR + j);
        float4 a2 = *(const float4*)(rw + (tq * 4 + 2) * STR + j);
        float4 a3 = *(const float4*)(rw + (tq * 4 + 3) * STR + j);
        float4 b0 = *(const float4*)(kk + (sq * 4 + 0) * STR + j);
        float4 b1 = *(const float4*)(kk + (sq * 4 + 1) * STR + j);
        float4 b2 = *(const float4*)(kk + (sq * 4 + 2) * STR + j);
        float4 b3 = *(const float4*)(kk + (sq * 4 + 3) * STR + j);
        const float4 av[4] = {a0, a1, a2, a3};
        const float4 bv[4] = {b0, b1, b2, b3};
#pragma unroll
        for (int tt = 0; tt < 4; ++tt)
#pragma unroll
          for (int ss = 0; ss < 4; ++ss)
            acc[tt][ss] += av[tt].x * bv[ss].x + av[tt].y * bv[ss].y
                         + av[tt].z * bv[ss].z + av[tt].w * bv[ss].w;
      }
    }
#pragma unroll
    for (int tt = 0; tt < 4; ++tt)
#pragma unroll
      for (int ss = 0; ss < 4; ++ss) {
        int t = tq * 4 + tt, s = sq * 4 + ss;
        Ps[t * STR + s] = (s < t) ? acc[tt][ss] : (s == t ? diag[t] : 0.f);
      }
  }
  __syncthreads();

  // ---- O_intra[t][i] = sum_{s<=t} P[t][s] * v[s][i]  -> y
  {
    const int tq = tid >> 4, iq = tid & 15;
    float o[4][4] = {{0.f}};
    for (int s4 = 0; s4 <= tq; ++s4) {
#pragma unroll
      for (int ss = 0; ss < 4; ++ss) {
        const int s = s4 * 4 + ss;
        float4 vx = *(const float4*)(vv + s * STR + iq * 4);
        float p0 = Ps[(tq * 4 + 0) * STR + s];
        float p1 = Ps[(tq * 4 + 1) * STR + s];
        float p2 = Ps[(tq * 4 + 2) * STR + s];
        float p3 = Ps[(tq * 4 + 3) * STR + s];
        o[0][0] += p0 * vx.x; o[0][1] += p0 * vx.y; o[0][2] += p0 * vx.z; o[0][3] += p0 * vx.w;
        o[1][0] += p1 * vx.x; o[1][1] += p1 * vx.y; o[1][2] += p1 * vx.z; o[1][3] += p1 * vx.w;
        o[2][0] += p2 * vx.x; o[2][1] += p2 * vx.y; o[2][2] += p2 * vx.z; o[2][3] += p2 * vx.w;
        o[3][0] += p3 * vx.x; o[3][1] += p3 * vx.y; o[3][2] += p3 * vx.z; o[3][3] += p3 * vx.w;
      }
    }
#pragma unroll
    for (int tt = 0; tt < 4; ++tt) {
      float4 ov = {o[tt][0], o[tt][1], o[tt][2], o[tt][3]};
      *(float4*)(y + gbase + (size_t)(tq * 4 + tt) * C_ + iq * 4) = ov;
    }
  }

  // ---- U[j][i] = G[j] * sum_s k~[s][j] * v[s][i]
  {
    const int jq = tid >> 4, iq = tid & 15;
    float ua[4][4] = {{0.f}};
    for (int s = 0; s < 64; ++s) {
      float4 kx = *(const float4*)(kk + s * STR + jq * 4);
      float4 vx = *(const float4*)(vv + s * STR + iq * 4);
      ua[0][0] += kx.x * vx.x; ua[0][1] += kx.x * vx.y; ua[0][2] += kx.x * vx.z; ua[0][3] += kx.x * vx.w;
      ua[1][0] += kx.y * vx.x; ua[1][1] += kx.y * vx.y; ua[1][2] += kx.y * vx.z; ua[1][3] += kx.y * vx.w;
      ua[2][0] += kx.z * vx.x; ua[2][1] += kx.z * vx.y; ua[2][2] += kx.z * vx.z; ua[2][3] += kx.z * vx.w;
      ua[3][0] += kx.w * vx.x; ua[3][1] += kx.w * vx.y; ua[3][2] += kx.w * vx.z; ua[3][3] += kx.w * vx.w;
    }
    const size_t ub = ((size_t)bh * 16 + c) * 4096;
#pragma unroll
    for (int jj = 0; jj < 4; ++jj) {
      float g = Gl[jq * 4 + jj];
      float4 uv = {ua[jj][0] * g, ua[jj][1] * g, ua[jj][2] * g, ua[jj][3] * g};
      *(float4*)(U + ub + (size_t)(jq * 4 + jj) * 64 + iq * 4) = uv;
    }
  }

  // ---- write r' back (for phase C)
  {
    const int t = tid >> 2, q = tid & 3;
#pragma unroll
    for (int p = 0; p < 4; ++p)
      *(float4*)(rp + gbase + (size_t)t * C_ + q * 16 + p * 4) =
          *(const float4*)(rw + t * STR + q * 16 + p * 4);
  }
}

__global__ __launch_bounds__(256)
void wkv_b(const float* __restrict__ U, const float* __restrict__ G,
           float* __restrict__ Sbuf)
{
  const int bh = blockIdx.x;
  const int tid = threadIdx.x;
  const int i = tid & 63, jq = tid >> 6;
  __shared__ float Gl[64];
  float S[16];
#pragma unroll
  for (int jj = 0; jj < 16; ++jj) S[jj] = 0.f;
  for (int c = 0; c < 16; ++c) {
    if (tid < 64) Gl[tid] = G[((size_t)bh * 16 + c) * 64 + tid];
    __syncthreads();
    const size_t base = ((size_t)bh * 16 + c) * 4096;
#pragma unroll
    for (int jj = 0; jj < 16; ++jj) {
      const int j = jq * 16 + jj;
      Sbuf[base + (size_t)j * 64 + i] = S[jj];
      S[jj] = Gl[j] * S[jj] + U[base + (size_t)j * 64 + i];
    }
    __syncthreads();
  }
}

__global__ __launch_bounds__(256)
void wkv_c(const float* __restrict__ rp, const float* __restrict__ Sbuf,
           float* __restrict__ y)
{
  __shared__ float Sl[64 * 68];
  __shared__ float rl[64 * 68];
  const int blk = blockIdx.x;
  const int bh = blk >> 4, c = blk & 15;
  const int b = bh >> 5, h = bh & 31;
  const int tid = threadIdx.x;
  const size_t gbase = ((size_t)(b * T_ + c * 64)) * C_ + h * 64;
  {
    const int t = tid >> 2, q = tid & 3;
    const size_t sb = ((size_t)bh * 16 + c) * 4096 + (size_t)t * 64 + q * 16;
    const size_t gr = gbase + (size_t)t * C_ + q * 16;
    const int l = t * 68 + q * 16;
#pragma unroll
    for (int p = 0; p < 4; ++p) {
      *(float4*)(rl + l + p * 4) = *(const float4*)(rp + gr + p * 4);
      *(float4*)(Sl + l + p * 4) = *(const float4*)(Sbuf + sb + p * 4);
    }
  }
  __syncthreads();
  const int tq = tid >> 4, iq = tid & 15;
  float o[4][4] = {{0.f}};
  for (int j = 0; j < 64; ++j) {
    float4 sv = *(const float4*)(Sl + j * 68 + iq * 4);
    float r0 = rl[(tq * 4 + 0) * 68 + j];
    float r1 = rl[(tq * 4 + 1) * 68 + j];
    float r2 = rl[(tq * 4 + 2) * 68 + j];
    float r3 = rl[(tq * 4 + 3) * 68 + j];
    o[0][0] += r0 * sv.x; o[0][1] += r0 * sv.y; o[0][2] += r0 * sv.z; o[0][3] += r0 * sv.w;
    o[1][0] += r1 * sv.x; o[1][1] += r1 * sv.y; o[1][2] += r1 * sv.z; o[1][3] += r1 * sv.w;
    o[2][0] += r2 * sv.x; o[2][1] += r2 * sv.y; o[2][2] += r2 * sv.z; o[2][3] += r2 * sv.w;
    o[3][0] += r3 * sv.x; o[3][1] += r3 * sv.y; o[3][2] += r3 * sv.z; o[3][3] += r3 * sv.w;
  }
#pragma unroll
  for (int tt = 0; tt < 4; ++tt) {
    float* yp = y + gbase + (size_t)(tq * 4 + tt) * C_ + iq * 4;
    float4 yv = *(const float4*)yp;
    yv.x += o[tt][0]; yv.y += o[tt][1]; yv.z += o[tt][2]; yv.w += o[tt][3];
    *(float4*)yp = yv;
  }
}

// ---------------------------------------------------------------------------
// GroupNorm(32 groups of 64) * silu(gpre) -> bf16
// ---------------------------------------------------------------------------
__global__ __launch_bounds__(256)
void gnorm_kernel(const float* __restrict__ y, const float* __restrict__ gpre,
                  const float* __restrict__ lng, const float* __restrict__ lnb,
                  bfu16* __restrict__ yg)
{
  const int bt = blockIdx.x;
  const int wv = threadIdx.x >> 6, lane = threadIdx.x & 63;
#pragma unroll
  for (int it = 0; it < 8; ++it) {
    int hh = it * 4 + wv;
    int c = hh * 64 + lane;
    size_t idx = (size_t)bt * C_ + c;
    float yv = y[idx];
    float s = yv, sq = yv * yv;
#pragma unroll
    for (int m = 1; m < 64; m <<= 1) {
      s  += __shfl_xor(s, m, 64);
      sq += __shfl_xor(sq, m, 64);
    }
    float mu  = s * (1.f / 64.f);
    float var = sq * (1.f / 64.f) - mu * mu;
    float yn  = (yv - mu) * rsqrtf(var + EPS_GN);
    yn = yn * lng[c] + lnb[c];
    float gp = gpre[idx];
    float gs = gp / (1.f + __expf(-gp));
    yg[idx] = f2b(yn * gs);
  }
}

// ---------------------------------------------------------------------------
extern "C" void kernel_launch(void* const* d_in, const int* in_sizes, int n_in,
                              void* d_out, int out_size, void* d_ws, size_t ws_size,
                              hipStream_t stream)
{
  const float* x      = (const float*)d_in[0];
  const float* maa_x  = (const float*)d_in[1];
  const float* maa_w  = (const float*)d_in[2];
  const float* maa_k  = (const float*)d_in[3];
  const float* maa_v  = (const float*)d_in[4];
  const float* maa_r  = (const float*)d_in[5];
  const float* maa_g  = (const float*)d_in[6];
  const float* tdec   = (const float*)d_in[7];
  const float* u      = (const float*)d_in[8];
  const float* maa_w1 = (const float*)d_in[9];
  const float* maa_w2 = (const float*)d_in[10];
  const float* td_w1  = (const float*)d_in[11];
  const float* td_w2  = (const float*)d_in[12];
  const float* Wmats[5] = { (const float*)d_in[13], (const float*)d_in[14],
                            (const float*)d_in[15], (const float*)d_in[16],
                            (const float*)d_in[17] };
  const float* lng = (const float*)d_in[18];
  const float* lnb = (const float*)d_in[19];
  float* out = (float*)d_out;

  char* wsp = (char*)d_ws;
  auto alloc = [&](size_t bytes) -> char* {
    char* p = wsp;
    wsp += (bytes + 255) & ~(size_t)255;
    return p;
  };

  bfu16* WT[5];
  for (int i = 0; i < 5; ++i) WT[i] = (bfu16*)alloc((size_t)2048 * 2048 * 2);
  bfu16* w1T  = (bfu16*)alloc((size_t)256 * 2048 * 2);   // maa_w1^T padded 160->256 rows
  bfu16* tw1T = (bfu16*)alloc((size_t)128 * 2048 * 2);   // td_w1^T padded 64->128 rows
  bfu16* tw2T = (bfu16*)alloc((size_t)2048 * 64 * 2);    // td_w2^T
  bfu16* w2T  = (bfu16*)alloc((size_t)5 * 2048 * 64 * 2);// maa_w2^T per f, K-pad 32->64
  float* xxb  = (float*)alloc((size_t)BT_ * C_ * 4);
  bfu16* xxx  = (bfu16*)alloc((size_t)BT_ * C_ * 2);
  bfu16* mtan = (bfu16*)alloc((size_t)5 * BT_ * 64 * 2); // tanh(xxx@maa_w1), K-pad
  bfu16* xmix[5];
  for (int f = 0; f < 5; ++f) xmix[f] = (bfu16*)alloc((size_t)BT_ * C_ * 2);
  float* rbuf = (float*)alloc((size_t)BT_ * C_ * 4);
  float* kbuf = (float*)alloc((size_t)BT_ * C_ * 4);
  float* vbuf = (float*)alloc((size_t)BT_ * C_ * 4);
  float* gbuf = (float*)alloc((size_t)BT_ * C_ * 4);
  float* wbuf = (float*)alloc((size_t)BT_ * C_ * 4);
  bfu16* wtan = (bfu16*)alloc((size_t)BT_ * 64 * 2);
  // Aliases (each dead-by-then, stream-ordered):
  float* ybuf = (float*)xxb;        // y over xx
  bfu16* ygb  = xxx;                // normed*silu output over xxx
  float* Ubuf = (float*)xmix[1];    // 16 MB over xmix[1..2]
  float* Sbuf = (float*)xmix[3];    // 16 MB over xmix[3..4]
  float* Gbuf = (float*)wtan;       // 256 KB, exactly wtan's size

  // Zero the K/N pad regions (deterministic every call)
  hipMemsetAsync(w1T,  0, (size_t)256 * 2048 * 2, stream);
  hipMemsetAsync(tw1T, 0, (size_t)128 * 2048 * 2, stream);
  hipMemsetAsync(w2T,  0, (size_t)5 * 2048 * 64 * 2, stream);
  hipMemsetAsync(mtan, 0, (size_t)5 * BT_ * 64 * 2, stream);

  dim3 tb(256);
  auto tr = [&](const float* s, bfu16* dptr, int R, int Cc, int ldd) {
    dim3 g((Cc + 31) / 32, (R + 31) / 32);
    transpose_f2b<<<g, tb, 0, stream>>>(s, dptr, R, Cc, ldd);
  };
  for (int i = 0; i < 5; ++i) tr(Wmats[i], WT[i], 2048, 2048, 2048);
  tr(maa_w1, w1T, 2048, 160, 2048);
  tr(td_w1, tw1T, 2048, 64, 2048);
  tr(td_w2, tw2T, 64, 2048, 64);
  for (int f = 0; f < 5; ++f)
    tr(maa_w2 + (size_t)f * 32 * 2048, w2T + (size_t)f * 2048 * 64, 32, 2048, 64);

  // token shift + xxx
  prep_xx<<<dim3((BT_ * C_ / 4) / 256), tb, 0, stream>>>(x, maa_x, xxb, xxx);

  // m = tanh(xxx @ maa_w1)  -> mtan[5][BT][64] scatter
  {
    EpiArgs e{}; e.ob = mtan; e.nout = 160;
    gemm_bt<1><<<dim3(2, 16), tb, 0, stream>>>(xxx, w1T, BT_, 2048, e);
  }

  // einsum + token-mix epilogue: xmix[f] = bf16(x + xx*(maa_f + m_f))
  const float* maas[5] = { maa_w, maa_k, maa_v, maa_r, maa_g };
  for (int f = 0; f < 5; ++f) {
    EpiArgs e{}; e.ob = xmix[f]; e.x = x; e.xx = xxb; e.vec = maas[f]; e.nout = 2048;
    gemm_bt<2><<<dim3(16, 16), tb, 0, stream>>>(mtan + (size_t)f * BT_ * 64,
                                                w2T + (size_t)f * 2048 * 64, BT_, 64, e);
  }

  // r,k,v,gpre big GEMMs (xr=f3, xk=f1, xv=f2, xg=f4)
  {
    EpiArgs e{}; e.ldo = 2048;
    e.of = rbuf; gemm_bt<0><<<dim3(16, 16), tb, 0, stream>>>(xmix[3], WT[0], BT_, 2048, e);
    e.of = kbuf; gemm_bt<0><<<dim3(16, 16), tb, 0, stream>>>(xmix[1], WT[1], BT_, 2048, e);
    e.of = vbuf; gemm_bt<0><<<dim3(16, 16), tb, 0, stream>>>(xmix[2], WT[2], BT_, 2048, e);
    e.of = gbuf; gemm_bt<0><<<dim3(16, 16), tb, 0, stream>>>(xmix[4], WT[3], BT_, 2048, e);
  }

  // w path: wtan = tanh(xw @ td_w1) ; w = time_decay + wtan @ td_w2
  {
    EpiArgs e{}; e.ob = wtan; e.nout = 64;
    gemm_bt<3><<<dim3(1, 16), tb, 0, stream>>>(xmix[0], tw1T, BT_, 2048, e);
  }
  {
    EpiArgs e{}; e.of = wbuf; e.vec = tdec;
    gemm_bt<4><<<dim3(16, 16), tb, 0, stream>>>(wtan, tw2T, BT_, 64, e);
  }

  // chunked WKV6
  wkv_a<<<dim3(1024), tb, 0, stream>>>(rbuf, kbuf, vbuf, wbuf, u, rbuf, ybuf, Ubuf, Gbuf);
  wkv_b<<<dim3(64),   tb, 0, stream>>>(Ubuf, Gbuf, Sbuf);
  wkv_c<<<dim3(1024), tb, 0, stream>>>(rbuf, Sbuf, ybuf);

  // GroupNorm * silu(g)
  gnorm_kernel<<<dim3(BT_), tb, 0, stream>>>(ybuf, gbuf, lng, lnb, ygb);

  // out = yg @ Wo
  {
    EpiArgs e{}; e.of = out; e.ldo = 2048;
    gemm_bt<0><<<dim3(16, 16), tb, 0, stream>>>(ygb, WT[4], BT_, 2048, e);
  }
}

// Round 3
// 373.903 us; speedup vs baseline: 2.7271x; 1.4772x over previous
//
#include <hip/hip_runtime.h>
#include <cstdint>
#include <cstddef>

// Problem constants (fixed by the reference)
#define B_  2
#define T_  1024
#define C_  2048
#define H_  32
#define BT_ (B_*T_)
static constexpr float EPS_GN = 1e-5f * 64.0f;

using short8 = __attribute__((ext_vector_type(8))) short;
using f32x4  = __attribute__((ext_vector_type(4))) float;
typedef unsigned short bfu16;

__device__ __forceinline__ bfu16 f2b(float f) {
  uint32_t x = __float_as_uint(f);
  uint32_t r = (x + 0x7FFFu + ((x >> 16) & 1u)) >> 16;
  return (bfu16)r;
}

__device__ __forceinline__ void gload16(const bfu16* g, bfu16* l) {
  __builtin_amdgcn_global_load_lds((__attribute__((address_space(1))) void*)g,
                                   (__attribute__((address_space(3))) void*)l,
                                   16, 0, 0);
}

// ---------------------------------------------------------------------------
// Unified bf16 MFMA GEMM, tile 128x128, BK=64, 4 waves (2x2 of 4x4 frags).
// B pre-transposed: Bt[N][K] row-major bf16.  ldk = row stride of A and Bt.
// MODE 4: of[row*ldo+col] = vArr[0][col] + acc               (w = tdec + ...)
// MODE 5: split-K partial: of[z*pStride + row*ldo + col] = acc, K-chunk z
// MODE 6: batched-4: A=aArr[z], Bt+=z*bStr, (of+z*oStr)=acc  (r,k,v,g)
// MODE 7: batched-5 token-mix: ob[z][idx]=bf16(x+xx*(vArr[z][col]+acc))
// ---------------------------------------------------------------------------
struct GemmP {
  const bfu16* A; const bfu16* Bt;
  float* of; bfu16* ob;
  const float* x; const float* xx;
  int ldk, kIters, kChunk, ldo;
  size_t pStride, aStr, bStr, oStr;
  const bfu16* aArr[4];
  const float* vArr[5];
};

template<int MODE>
__global__ __launch_bounds__(256)
void gemm_k(GemmP p)
{
  __shared__ alignas(16) bfu16 As[128*64];
  __shared__ alignas(16) bfu16 Bs[128*64];
  const int tid  = threadIdx.x;
  const int z    = blockIdx.z;
  const int m0   = blockIdx.y * 128, n0 = blockIdx.x * 128;
  const int lane = tid & 63;
  const int wv   = tid >> 6;
  const int wr   = (wv >> 1) * 64, wc = (wv & 1) * 64;

  const bfu16* A  = p.A;
  const bfu16* Bt = p.Bt;
  size_t koff = 0;
  if constexpr (MODE == 6) { A = p.aArr[z]; Bt += (size_t)z * p.bStr; }
  if constexpr (MODE == 7) { A += (size_t)z * p.aStr; Bt += (size_t)z * p.bStr; }
  if constexpr (MODE == 5) { koff = (size_t)z * p.kChunk; }

  f32x4 acc[4][4];
  const f32x4 zero = {0.f, 0.f, 0.f, 0.f};
#pragma unroll
  for (int i = 0; i < 4; ++i)
#pragma unroll
    for (int j = 0; j < 4; ++j) acc[i][j] = zero;

  const int srow = tid >> 3;        // 0..31
  const int scol = (tid & 7) * 8;   // 0..56
  const int ldk  = p.ldk;

  for (int kb = 0; kb < p.kIters; ++kb) {
    const bfu16* ga = A  + (size_t)m0 * ldk + koff + kb * 64;
    const bfu16* gb = Bt + (size_t)n0 * ldk + koff + kb * 64;
#pragma unroll
    for (int it = 0; it < 4; ++it) {
      int r = it * 32 + srow;
      gload16(ga + (size_t)r * ldk + scol, As + r * 64 + scol);
      gload16(gb + (size_t)r * ldk + scol, Bs + r * 64 + scol);
    }
    __syncthreads();
#pragma unroll
    for (int kk = 0; kk < 2; ++kk) {
      const int ko = kk * 32 + (lane >> 4) * 8;
      short8 a[4], b[4];
#pragma unroll
      for (int i = 0; i < 4; ++i)
        a[i] = *(const short8*)(As + (wr + i * 16 + (lane & 15)) * 64 + ko);
#pragma unroll
      for (int j = 0; j < 4; ++j)
        b[j] = *(const short8*)(Bs + (wc + j * 16 + (lane & 15)) * 64 + ko);
#pragma unroll
      for (int i = 0; i < 4; ++i)
#pragma unroll
        for (int j = 0; j < 4; ++j)
          acc[i][j] = __builtin_amdgcn_mfma_f32_16x16x32_bf16(a[i], b[j], acc[i][j], 0, 0, 0);
    }
    __syncthreads();
  }

  const int cb = n0 + wc + (lane & 15);
  const int rb = m0 + wr + ((lane >> 4) << 2);
#pragma unroll
  for (int i = 0; i < 4; ++i) {
#pragma unroll
    for (int j = 0; j < 4; ++j) {
      int col = cb + j * 16;
#pragma unroll
      for (int q = 0; q < 4; ++q) {
        int row = rb + i * 16 + q;
        float v = acc[i][j][q];
        if constexpr (MODE == 4) {
          p.of[(size_t)row * p.ldo + col] = p.vArr[0][col] + v;
        } else if constexpr (MODE == 5) {
          p.of[(size_t)z * p.pStride + (size_t)row * p.ldo + col] = v;
        } else if constexpr (MODE == 6) {
          (p.of + (size_t)z * p.oStr)[(size_t)row * 2048 + col] = v;
        } else if constexpr (MODE == 7) {
          size_t idx = (size_t)row * C_ + col;
          (p.ob + (size_t)z * p.oStr)[idx] =
              f2b(p.x[idx] + p.xx[idx] * (p.vArr[z][col] + v));
        }
      }
    }
  }
}

// ---------------------------------------------------------------------------
// split-K reduce + tanh -> bf16.  OUT=0: mtan scatter [f][row][d]; OUT=1: wtan.
// ---------------------------------------------------------------------------
template<int OUT>
__global__ __launch_bounds__(256)
void redk_tanh(const float* __restrict__ part, size_t pStr, int ldo, int ncols,
               bfu16* __restrict__ out)
{
  int id = blockIdx.x * 256 + threadIdx.x;
  int row = id / ncols, col = id % ncols;
  if (row >= BT_) return;
  float v = 0.f;
#pragma unroll
  for (int s = 0; s < 8; ++s) v += part[(size_t)s * pStr + (size_t)row * ldo + col];
  bfu16 tv = f2b(tanhf(v));
  if constexpr (OUT == 0)
    out[((size_t)(col >> 5) * BT_ + row) * 64 + (col & 31)] = tv;
  else
    out[(size_t)row * 64 + col] = tv;
}

__global__ __launch_bounds__(256)
void redk_sum2(const float* __restrict__ p0, float* __restrict__ out)
{
  size_t i = ((size_t)blockIdx.x * 256 + threadIdx.x) * 4;
  float4 a = *(const float4*)(p0 + i);
  float4 b = *(const float4*)(p0 + (size_t)2048 * 2048 + i);
  a.x += b.x; a.y += b.y; a.z += b.z; a.w += b.w;
  *(float4*)(out + i) = a;
}

// ---------------------------------------------------------------------------
// f32 [R][Cc] -> bf16 dst[c*ldd + r], batched over z (src[z], dst+z*dStr).
// Rows r in [R, Rpad) of dst are zero-filled (K-pad for GEMM B operands).
// ---------------------------------------------------------------------------
struct TrP { const float* src[5]; bfu16* dst; size_t dStr; int R, Cc, Rpad, ldd; };

__global__ __launch_bounds__(256)
void transpose_k(TrP p)
{
  __shared__ float tile[32][33];
  const float* src = p.src[blockIdx.z];
  bfu16* dst = p.dst + (size_t)blockIdx.z * p.dStr;
  const int tx = threadIdx.x & 31, ty = threadIdx.x >> 5;
  const int r0 = blockIdx.y * 32, c0 = blockIdx.x * 32;
#pragma unroll
  for (int i = 0; i < 4; ++i) {
    int r = r0 + ty + i * 8, c = c0 + tx;
    tile[ty + i * 8][tx] = (r < p.R && c < p.Cc) ? src[(size_t)r * p.Cc + c] : 0.f;
  }
  __syncthreads();
#pragma unroll
  for (int i = 0; i < 4; ++i) {
    int c = c0 + ty + i * 8, r = r0 + tx;
    if (c < p.Cc && r < p.Rpad) dst[(size_t)c * p.ldd + r] = f2b(tile[tx][ty + i * 8]);
  }
}

// ---------------------------------------------------------------------------
// xx = shift(x) - x ; xxx = bf16(x + xx*maa_x)
// ---------------------------------------------------------------------------
__global__ __launch_bounds__(256)
void prep_xx(const float* __restrict__ x, const float* __restrict__ maa_x,
             float* __restrict__ xx, bfu16* __restrict__ xxx)
{
  size_t i = ((size_t)blockIdx.x * 256 + threadIdx.x) * 4;
  int c  = (int)(i & (C_ - 1));
  int bt = (int)(i >> 11);
  int t  = bt & (T_ - 1);
  float4 xv = *(const float4*)(x + i);
  float4 xp = {0.f, 0.f, 0.f, 0.f};
  if (t > 0) xp = *(const float4*)(x + i - C_);
  float4 mx = *(const float4*)(maa_x + c);
  float4 d;
  d.x = xp.x - xv.x; d.y = xp.y - xv.y; d.z = xp.z - xv.z; d.w = xp.w - xv.w;
  *(float4*)(xx + i) = d;
  xxx[i + 0] = f2b(xv.x + d.x * mx.x);
  xxx[i + 1] = f2b(xv.y + d.y * mx.y);
  xxx[i + 2] = f2b(xv.z + d.z * mx.z);
  xxx[i + 3] = f2b(xv.w + d.w * mx.w);
}

// ---------------------------------------------------------------------------
// WKV6 chunked scan (unchanged from round 2).
// ---------------------------------------------------------------------------
#define STR 76

__global__ __launch_bounds__(256)
void wkv_a(const float* __restrict__ r, const float* __restrict__ k,
           const float* __restrict__ v, const float* __restrict__ w,
           const float* __restrict__ u, float* __restrict__ rp,
           float* __restrict__ y, float* __restrict__ U, float* __restrict__ G)
{
  __shared__ float rw[64 * STR];
  __shared__ float kk[64 * STR];
  __shared__ float vv[64 * STR];
  __shared__ float Ps[64 * STR];
  __shared__ float red[4][64];
  __shared__ float diag[64];
  __shared__ float Gl[64];

  const int blk = blockIdx.x;
  const int bh = blk >> 4, c = blk & 15;
  const int b = bh >> 5, h = bh & 31;
  const int tid = threadIdx.x;
  const size_t gbase = ((size_t)(b * T_ + c * 64)) * C_ + h * 64;

  {
    const int t = tid >> 2, q = tid & 3;
    const size_t g = gbase + (size_t)t * C_ + q * 16;
    const int l = t * STR + q * 16;
#pragma unroll
    for (int p = 0; p < 4; ++p) {
      *(float4*)(rw + l + p * 4) = *(const float4*)(r + g + p * 4);
      *(float4*)(kk + l + p * 4) = *(const float4*)(k + g + p * 4);
      *(float4*)(vv + l + p * 4) = *(const float4*)(v + g + p * 4);
      float4 wv = *(const float4*)(w + g + p * 4);
      float4 lw;
      lw.x = -__expf(wv.x); lw.y = -__expf(wv.y);
      lw.z = -__expf(wv.z); lw.w = -__expf(wv.w);
      *(float4*)(Ps + l + p * 4) = lw;
    }
  }
  __syncthreads();

  if (tid < 64) {
    const int j = tid;
    const float uj = u[h * 64 + j];
    float cs = 0.f;
    for (int t = 0; t < 64; ++t) {
      const int a = t * STR + j;
      float lw = Ps[a];
      float rv = rw[a] * __expf(cs);
      rw[a] = rv;
      cs += lw;
      float kv = kk[a] * __expf(-cs);
      kk[a] = kv;
      Ps[a] = rv * kv * uj * __expf(lw);
    }
    float Gj = __expf(cs);
    Gl[j] = Gj;
    G[((size_t)bh * 16 + c) * 64 + j] = Gj;
  }
  __syncthreads();

  {
    const int t = tid & 63, q = tid >> 6;
    float s = 0.f;
#pragma unroll
    for (int jj = 0; jj < 16; ++jj) s += Ps[t * STR + q * 16 + jj];
    red[q][t] = s;
  }
  __syncthreads();
  if (tid < 64) diag[tid] = red[0][tid] + red[1][tid] + red[2][tid] + red[3][tid];
  __syncthreads();

  {
    const int tq = tid >> 4, sq = tid & 15;
    float acc[4][4] = {{0.f}};
    if (sq <= tq) {
      for (int j = 0; j < 64; j += 4) {
        float4 a0 = *(const float4*)(rw + (tq * 4 + 0) * STR + j);
        float4 a1 = *(const float4*)(rw + (tq * 4 + 1) * STR + j);
        float4 a2 = *(const float4*)(rw + (tq * 4 + 2) * STR + j);
        float4 a3 = *(const float4*)(rw + (tq * 4 + 3) * STR + j);
        float4 b0 = *(const float4*)(kk + (sq * 4 + 0) * STR + j);
        float4 b1 = *(const float4*)(kk + (sq * 4 + 1) * STR + j);
        float4 b2 = *(const float4*)(kk + (sq * 4 + 2) * STR + j);
        float4 b3 = *(const float4*)(kk + (sq * 4 + 3) * STR + j);
        const float4 av[4] = {a0, a1, a2, a3};
        const float4 bv[4] = {b0, b1, b2, b3};
#pragma unroll
        for (int tt = 0; tt < 4; ++tt)
#pragma unroll
          for (int ss = 0; ss < 4; ++ss)
            acc[tt][ss] += av[tt].x * bv[ss].x + av[tt].y * bv[ss].y
                         + av[tt].z * bv[ss].z + av[tt].w * bv[ss].w;
      }
    }
#pragma unroll
    for (int tt = 0; tt < 4; ++tt)
#pragma unroll
      for (int ss = 0; ss < 4; ++ss) {
        int t = tq * 4 + tt, s = sq * 4 + ss;
        Ps[t * STR + s] = (s < t) ? acc[tt][ss] : (s == t ? diag[t] : 0.f);
      }
  }
  __syncthreads();

  {
    const int tq = tid >> 4, iq = tid & 15;
    float o[4][4] = {{0.f}};
    for (int s4 = 0; s4 <= tq; ++s4) {
#pragma unroll
      for (int ss = 0; ss < 4; ++ss) {
        const int s = s4 * 4 + ss;
        float4 vx = *(const float4*)(vv + s * STR + iq * 4);
        float p0 = Ps[(tq * 4 + 0) * STR + s];
        float p1 = Ps[(tq * 4 + 1) * STR + s];
        float p2 = Ps[(tq * 4 + 2) * STR + s];
        float p3 = Ps[(tq * 4 + 3) * STR + s];
        o[0][0] += p0 * vx.x; o[0][1] += p0 * vx.y; o[0][2] += p0 * vx.z; o[0][3] += p0 * vx.w;
        o[1][0] += p1 * vx.x; o[1][1] += p1 * vx.y; o[1][2] += p1 * vx.z; o[1][3] += p1 * vx.w;
        o[2][0] += p2 * vx.x; o[2][1] += p2 * vx.y; o[2][2] += p2 * vx.z; o[2][3] += p2 * vx.w;
        o[3][0] += p3 * vx.x; o[3][1] += p3 * vx.y; o[3][2] += p3 * vx.z; o[3][3] += p3 * vx.w;
      }
    }
#pragma unroll
    for (int tt = 0; tt < 4; ++tt) {
      float4 ov = {o[tt][0], o[tt][1], o[tt][2], o[tt][3]};
      *(float4*)(y + gbase + (size_t)(tq * 4 + tt) * C_ + iq * 4) = ov;
    }
  }

  {
    const int jq = tid >> 4, iq = tid & 15;
    float ua[4][4] = {{0.f}};
    for (int s = 0; s < 64; ++s) {
      float4 kx = *(const float4*)(kk + s * STR + jq * 4);
      float4 vx = *(const float4*)(vv + s * STR + iq * 4);
      ua[0][0] += kx.x * vx.x; ua[0][1] += kx.x * vx.y; ua[0][2] += kx.x * vx.z; ua[0][3] += kx.x * vx.w;
      ua[1][0] += kx.y * vx.x; ua[1][1] += kx.y * vx.y; ua[1][2] += kx.y * vx.z; ua[1][3] += kx.y * vx.w;
      ua[2][0] += kx.z * vx.x; ua[2][1] += kx.z * vx.y; ua[2][2] += kx.z * vx.z; ua[2][3] += kx.z * vx.w;
      ua[3][0] += kx.w * vx.x; ua[3][1] += kx.w * vx.y; ua[3][2] += kx.w * vx.z; ua[3][3] += kx.w * vx.w;
    }
    const size_t ub = ((size_t)bh * 16 + c) * 4096;
#pragma unroll
    for (int jj = 0; jj < 4; ++jj) {
      float g = Gl[jq * 4 + jj];
      float4 uv = {ua[jj][0] * g, ua[jj][1] * g, ua[jj][2] * g, ua[jj][3] * g};
      *(float4*)(U + ub + (size_t)(jq * 4 + jj) * 64 + iq * 4) = uv;
    }
  }

  {
    const int t = tid >> 2, q = tid & 3;
#pragma unroll
    for (int p = 0; p < 4; ++p)
      *(float4*)(rp + gbase + (size_t)t * C_ + q * 16 + p * 4) =
          *(const float4*)(rw + t * STR + q * 16 + p * 4);
  }
}

__global__ __launch_bounds__(256)
void wkv_b(const float* __restrict__ U, const float* __restrict__ G,
           float* __restrict__ Sbuf)
{
  const int bh = blockIdx.x;
  const int tid = threadIdx.x;
  const int i = tid & 63, jq = tid >> 6;
  __shared__ float Gl[64];
  float S[16];
#pragma unroll
  for (int jj = 0; jj < 16; ++jj) S[jj] = 0.f;
  for (int c = 0; c < 16; ++c) {
    if (tid < 64) Gl[tid] = G[((size_t)bh * 16 + c) * 64 + tid];
    __syncthreads();
    const size_t base = ((size_t)bh * 16 + c) * 4096;
#pragma unroll
    for (int jj = 0; jj < 16; ++jj) {
      const int j = jq * 16 + jj;
      Sbuf[base + (size_t)j * 64 + i] = S[jj];
      S[jj] = Gl[j] * S[jj] + U[base + (size_t)j * 64 + i];
    }
    __syncthreads();
  }
}

__global__ __launch_bounds__(256)
void wkv_c(const float* __restrict__ rp, const float* __restrict__ Sbuf,
           float* __restrict__ y)
{
  __shared__ float Sl[64 * 68];
  __shared__ float rl[64 * 68];
  const int blk = blockIdx.x;
  const int bh = blk >> 4, c = blk & 15;
  const int b = bh >> 5, h = bh & 31;
  const int tid = threadIdx.x;
  const size_t gbase = ((size_t)(b * T_ + c * 64)) * C_ + h * 64;
  {
    const int t = tid >> 2, q = tid & 3;
    const size_t sb = ((size_t)bh * 16 + c) * 4096 + (size_t)t * 64 + q * 16;
    const size_t gr = gbase + (size_t)t * C_ + q * 16;
    const int l = t * 68 + q * 16;
#pragma unroll
    for (int p = 0; p < 4; ++p) {
      *(float4*)(rl + l + p * 4) = *(const float4*)(rp + gr + p * 4);
      *(float4*)(Sl + l + p * 4) = *(const float4*)(Sbuf + sb + p * 4);
    }
  }
  __syncthreads();
  const int tq = tid >> 4, iq = tid & 15;
  float o[4][4] = {{0.f}};
  for (int j = 0; j < 64; ++j) {
    float4 sv = *(const float4*)(Sl + j * 68 + iq * 4);
    float r0 = rl[(tq * 4 + 0) * 68 + j];
    float r1 = rl[(tq * 4 + 1) * 68 + j];
    float r2 = rl[(tq * 4 + 2) * 68 + j];
    float r3 = rl[(tq * 4 + 3) * 68 + j];
    o[0][0] += r0 * sv.x; o[0][1] += r0 * sv.y; o[0][2] += r0 * sv.z; o[0][3] += r0 * sv.w;
    o[1][0] += r1 * sv.x; o[1][1] += r1 * sv.y; o[1][2] += r1 * sv.z; o[1][3] += r1 * sv.w;
    o[2][0] += r2 * sv.x; o[2][1] += r2 * sv.y; o[2][2] += r2 * sv.z; o[2][3] += r2 * sv.w;
    o[3][0] += r3 * sv.x; o[3][1] += r3 * sv.y; o[3][2] += r3 * sv.z; o[3][3] += r3 * sv.w;
  }
#pragma unroll
  for (int tt = 0; tt < 4; ++tt) {
    float* yp = y + gbase + (size_t)(tq * 4 + tt) * C_ + iq * 4;
    float4 yv = *(const float4*)yp;
    yv.x += o[tt][0]; yv.y += o[tt][1]; yv.z += o[tt][2]; yv.w += o[tt][3];
    *(float4*)yp = yv;
  }
}

// ---------------------------------------------------------------------------
// GroupNorm(32 groups of 64) * silu(gpre) -> bf16
// ---------------------------------------------------------------------------
__global__ __launch_bounds__(256)
void gnorm_kernel(const float* __restrict__ y, const float* __restrict__ gpre,
                  const float* __restrict__ lng, const float* __restrict__ lnb,
                  bfu16* __restrict__ yg)
{
  const int bt = blockIdx.x;
  const int wv = threadIdx.x >> 6, lane = threadIdx.x & 63;
#pragma unroll
  for (int it = 0; it < 8; ++it) {
    int hh = it * 4 + wv;
    int c = hh * 64 + lane;
    size_t idx = (size_t)bt * C_ + c;
    float yv = y[idx];
    float s = yv, sq = yv * yv;
#pragma unroll
    for (int m = 1; m < 64; m <<= 1) {
      s  += __shfl_xor(s, m, 64);
      sq += __shfl_xor(sq, m, 64);
    }
    float mu  = s * (1.f / 64.f);
    float var = sq * (1.f / 64.f) - mu * mu;
    float yn  = (yv - mu) * rsqrtf(var + EPS_GN);
    yn = yn * lng[c] + lnb[c];
    float gp = gpre[idx];
    float gs = gp / (1.f + __expf(-gp));
    yg[idx] = f2b(yn * gs);
  }
}

// ---------------------------------------------------------------------------
extern "C" void kernel_launch(void* const* d_in, const int* in_sizes, int n_in,
                              void* d_out, int out_size, void* d_ws, size_t ws_size,
                              hipStream_t stream)
{
  const float* x      = (const float*)d_in[0];
  const float* maa_x  = (const float*)d_in[1];
  const float* maa_w  = (const float*)d_in[2];
  const float* maa_k  = (const float*)d_in[3];
  const float* maa_v  = (const float*)d_in[4];
  const float* maa_r  = (const float*)d_in[5];
  const float* maa_g  = (const float*)d_in[6];
  const float* tdec   = (const float*)d_in[7];
  const float* u      = (const float*)d_in[8];
  const float* maa_w1 = (const float*)d_in[9];
  const float* maa_w2 = (const float*)d_in[10];
  const float* td_w1  = (const float*)d_in[11];
  const float* td_w2  = (const float*)d_in[12];
  const float* lng = (const float*)d_in[18];
  const float* lnb = (const float*)d_in[19];
  float* out = (float*)d_out;

  char* wsp = (char*)d_ws;
  auto alloc = [&](size_t bytes) -> char* {
    char* p = wsp;
    wsp += (bytes + 255) & ~(size_t)255;
    return p;
  };

  bfu16* WT0 = (bfu16*)alloc((size_t)5 * 2048 * 2048 * 2);  // WT[z] = WT0 + z*4M
  bfu16* w1T  = (bfu16*)alloc((size_t)256 * 2048 * 2);
  bfu16* tw1T = (bfu16*)alloc((size_t)128 * 2048 * 2);
  bfu16* tw2T = (bfu16*)alloc((size_t)2048 * 64 * 2);
  bfu16* w2T  = (bfu16*)alloc((size_t)5 * 2048 * 64 * 2);
  float* xxb  = (float*)alloc((size_t)BT_ * C_ * 4);
  bfu16* xxx  = (bfu16*)alloc((size_t)BT_ * C_ * 2);
  bfu16* mtan = (bfu16*)alloc((size_t)5 * BT_ * 64 * 2);
  bfu16* xmix0 = (bfu16*)alloc((size_t)5 * BT_ * C_ * 2); // xmix[f] = xmix0 + f*BT*C
  float* rbuf = (float*)alloc((size_t)4 * BT_ * C_ * 4);  // r,k,v,g contiguous
  float* kbuf = rbuf + (size_t)BT_ * C_;
  float* vbuf = kbuf + (size_t)BT_ * C_;
  float* gbuf = vbuf + (size_t)BT_ * C_;
  float* wbuf = (float*)alloc((size_t)BT_ * C_ * 4);
  bfu16* wtan = (bfu16*)alloc((size_t)BT_ * 64 * 2);
  // Aliases (dead-by-then, stream-ordered):
  float* ybuf = (float*)xxb;
  bfu16* ygb  = xxx;
  float* Ubuf = (float*)(xmix0 + (size_t)1 * BT_ * C_);  // 16MB over xmix[1..2]
  float* Sbuf = (float*)(xmix0 + (size_t)3 * BT_ * C_);  // 16MB over xmix[3..4]
  float* Gbuf = (float*)wtan;
  float* part1 = rbuf;   // EPI1 split-K partials [8][BT][256] = 16MB (pre-GEMM)
  float* part3 = wbuf;   // EPI3 split-K partials [8][BT][128] =  8MB (pre-MODE4)
  float* partW = rbuf;   // Wo   split-K partials [2][BT][2048] = 32MB (post-wkv)

  // mtan K-pad must stay finite/zero: its garbage would multiply real acc terms
  hipMemsetAsync(mtan, 0, (size_t)5 * BT_ * 64 * 2, stream);

  dim3 tb(256);

  // ---- transposes (f32 -> bf16, [R][C] -> dst[c][r]) ----
  {
    TrP p{}; for (int i = 0; i < 5; ++i) p.src[i] = (const float*)d_in[13 + i];
    p.dst = WT0; p.dStr = (size_t)2048 * 2048; p.R = 2048; p.Cc = 2048; p.Rpad = 2048; p.ldd = 2048;
    transpose_k<<<dim3(64, 64, 5), tb, 0, stream>>>(p);
  }
  {
    TrP p{}; p.src[0] = maa_w1; p.dst = w1T; p.dStr = 0;
    p.R = 2048; p.Cc = 160; p.Rpad = 2048; p.ldd = 2048;
    transpose_k<<<dim3(5, 64, 1), tb, 0, stream>>>(p);
  }
  {
    TrP p{}; p.src[0] = td_w1; p.dst = tw1T; p.dStr = 0;
    p.R = 2048; p.Cc = 64; p.Rpad = 2048; p.ldd = 2048;
    transpose_k<<<dim3(2, 64, 1), tb, 0, stream>>>(p);
  }
  {
    TrP p{}; p.src[0] = td_w2; p.dst = tw2T; p.dStr = 0;
    p.R = 64; p.Cc = 2048; p.Rpad = 64; p.ldd = 64;
    transpose_k<<<dim3(64, 2, 1), tb, 0, stream>>>(p);
  }
  {
    TrP p{}; for (int f = 0; f < 5; ++f) p.src[f] = maa_w2 + (size_t)f * 32 * 2048;
    p.dst = w2T; p.dStr = (size_t)2048 * 64;
    p.R = 32; p.Cc = 2048; p.Rpad = 64; p.ldd = 64;   // zero-fill K-pad rows 32..63
    transpose_k<<<dim3(64, 2, 5), tb, 0, stream>>>(p);
  }

  // ---- token shift + xxx ----
  prep_xx<<<dim3((BT_ * C_ / 4) / 256), tb, 0, stream>>>(x, maa_x, xxb, xxx);

  // ---- m-path: split-K GEMM (xxx @ maa_w1), 8 chunks of 256 ----
  {
    GemmP p{}; p.A = xxx; p.Bt = w1T; p.ldk = 2048; p.kIters = 4; p.kChunk = 256;
    p.ldo = 256; p.pStride = (size_t)BT_ * 256; p.of = part1;
    gemm_k<5><<<dim3(2, 16, 8), tb, 0, stream>>>(p);
  }
  redk_tanh<0><<<dim3(BT_ * 160 / 256), tb, 0, stream>>>(part1, (size_t)BT_ * 256, 256, 160, mtan);

  // ---- token-mix: batched-5 (mtan[f] @ w2T[f]) with x+xx epilogue ----
  {
    GemmP p{}; p.A = mtan; p.Bt = w2T; p.ldk = 64; p.kIters = 1;
    p.aStr = (size_t)BT_ * 64; p.bStr = (size_t)2048 * 64; p.oStr = (size_t)BT_ * C_;
    p.ob = xmix0; p.x = x; p.xx = xxb;
    p.vArr[0] = maa_w; p.vArr[1] = maa_k; p.vArr[2] = maa_v; p.vArr[3] = maa_r; p.vArr[4] = maa_g;
    gemm_k<7><<<dim3(16, 16, 5), tb, 0, stream>>>(p);
  }

  // ---- r,k,v,g: batched-4 full GEMMs (1024 blocks) ----
  {
    GemmP p{}; p.Bt = WT0; p.ldk = 2048; p.kIters = 32;
    p.bStr = (size_t)2048 * 2048; p.oStr = (size_t)BT_ * C_; p.of = rbuf;
    p.aArr[0] = xmix0 + (size_t)3 * BT_ * C_;  // xr
    p.aArr[1] = xmix0 + (size_t)1 * BT_ * C_;  // xk
    p.aArr[2] = xmix0 + (size_t)2 * BT_ * C_;  // xv
    p.aArr[3] = xmix0 + (size_t)4 * BT_ * C_;  // xg
    gemm_k<6><<<dim3(16, 16, 4), tb, 0, stream>>>(p);
  }

  // ---- w-path: split-K thin GEMM (xw @ td_w1) ----
  {
    GemmP p{}; p.A = xmix0; p.Bt = tw1T; p.ldk = 2048; p.kIters = 4; p.kChunk = 256;
    p.ldo = 128; p.pStride = (size_t)BT_ * 128; p.of = part3;
    gemm_k<5><<<dim3(1, 16, 8), tb, 0, stream>>>(p);
  }
  redk_tanh<1><<<dim3(BT_ * 64 / 256), tb, 0, stream>>>(part3, (size_t)BT_ * 128, 128, 64, wtan);

  // ---- w = tdec + wtan @ td_w2 ----
  {
    GemmP p{}; p.A = wtan; p.Bt = tw2T; p.ldk = 64; p.kIters = 1;
    p.of = wbuf; p.ldo = 2048; p.vArr[0] = tdec;
    gemm_k<4><<<dim3(16, 16, 1), tb, 0, stream>>>(p);
  }

  // ---- chunked WKV6 ----
  wkv_a<<<dim3(1024), tb, 0, stream>>>(rbuf, kbuf, vbuf, wbuf, u, rbuf, ybuf, Ubuf, Gbuf);
  wkv_b<<<dim3(64),   tb, 0, stream>>>(Ubuf, Gbuf, Sbuf);
  wkv_c<<<dim3(1024), tb, 0, stream>>>(rbuf, Sbuf, ybuf);

  // ---- GroupNorm * silu(g) ----
  gnorm_kernel<<<dim3(BT_), tb, 0, stream>>>(ybuf, gbuf, lng, lnb, ygb);

  // ---- out = yg @ Wo  (split-K=2 over 1024, partials then sum) ----
  {
    GemmP p{}; p.A = ygb; p.Bt = WT0 + (size_t)4 * 2048 * 2048;
    p.ldk = 2048; p.kIters = 16; p.kChunk = 1024;
    p.ldo = 2048; p.pStride = (size_t)BT_ * 2048; p.of = partW;
    gemm_k<5><<<dim3(16, 16, 2), tb, 0, stream>>>(p);
  }
  redk_sum2<<<dim3(4096), tb, 0, stream>>>(partW, out);
}